// Round 1
// baseline (251.680 us; speedup 1.0000x reference)
//
#include <hip/hip_runtime.h>

#define EPSF 1e-12f
#define GN 32
#define NPTS (GN * GN * GN)
#define FS 20   // floats per precomputed face record

// ---------------- kernel A: bboxes, center, scale, overlap ----------------
__global__ void k_setup(const float* __restrict__ hv, int nh,
                        const float* __restrict__ ov, int no,
                        float* __restrict__ hdr) {
    __shared__ float sred[256];
    int t = threadIdx.x;
    float hmin[3] = { INFINITY, INFINITY, INFINITY };
    float hmax[3] = { -INFINITY, -INFINITY, -INFINITY };
    float omin[3] = { INFINITY, INFINITY, INFINITY };
    float omax[3] = { -INFINITY, -INFINITY, -INFINITY };
    for (int i = t; i < nh; i += 256)
        for (int k = 0; k < 3; ++k) {
            float v = hv[3 * i + k];
            hmin[k] = fminf(hmin[k], v);
            hmax[k] = fmaxf(hmax[k], v);
        }
    for (int i = t; i < no; i += 256)
        for (int k = 0; k < 3; ++k) {
            float v = ov[3 * i + k];
            omin[k] = fminf(omin[k], v);
            omax[k] = fmaxf(omax[k], v);
        }
    float vals[12] = { hmin[0], hmin[1], hmin[2], hmax[0], hmax[1], hmax[2],
                       omin[0], omin[1], omin[2], omax[0], omax[1], omax[2] };
    float red[12];
    for (int c = 0; c < 12; ++c) {
        bool ismin = (c < 3) || (c >= 6 && c < 9);
        sred[t] = vals[c];
        __syncthreads();
        for (int s = 128; s > 0; s >>= 1) {
            if (t < s) sred[t] = ismin ? fminf(sred[t], sred[t + s])
                                       : fmaxf(sred[t], sred[t + s]);
            __syncthreads();
        }
        red[c] = sred[0];
        __syncthreads();
    }
    if (t == 0) {
        bool ovl = true;
        for (int k = 0; k < 3; ++k)
            ovl = ovl && (red[k] <= red[9 + k]) && (red[6 + k] <= red[3 + k]);
        float ext0 = __fsub_rn(red[3], red[0]);
        float ext1 = __fsub_rn(red[4], red[1]);
        float ext2 = __fsub_rn(red[5], red[2]);
        float m = fmaxf(ext0, fmaxf(ext1, ext2));
        hdr[0] = __fmul_rn(0.5f, __fadd_rn(red[0], red[3]));   // center
        hdr[1] = __fmul_rn(0.5f, __fadd_rn(red[1], red[4]));
        hdr[2] = __fmul_rn(0.5f, __fadd_rn(red[2], red[5]));
        hdr[3] = __fmul_rn(0.6f, m);                            // scale
        hdr[4] = ovl ? 1.0f : 0.0f;                             // overlap
    }
}

// ---------------- kernel B: per-face precompute (scaled verts) ----------------
__device__ __forceinline__ float dot_rn(const float* x, const float* y) {
    return __fadd_rn(__fadd_rn(__fmul_rn(x[0], y[0]), __fmul_rn(x[1], y[1])),
                     __fmul_rn(x[2], y[2]));
}

__global__ void k_faces(const float* __restrict__ hv, const int* __restrict__ faces,
                        int nf, const float* __restrict__ hdr, float* __restrict__ fd) {
    int f = blockIdx.x * blockDim.x + threadIdx.x;
    if (f >= nf) return;
    float c0 = hdr[0], c1 = hdr[1], c2 = hdr[2], sc = hdr[3];
    int ia = faces[3 * f + 0], ib = faces[3 * f + 1], ic = faces[3 * f + 2];
    float v0[3], v1[3], v2[3];
    for (int k = 0; k < 3; ++k) {
        float cen = (k == 0) ? c0 : ((k == 1) ? c1 : c2);
        v0[k] = __fdiv_rn(__fsub_rn(hv[3 * ia + k], cen), sc);
        v1[k] = __fdiv_rn(__fsub_rn(hv[3 * ib + k], cen), sc);
        v2[k] = __fdiv_rn(__fsub_rn(hv[3 * ic + k], cen), sc);
    }
    float e0[3], e1[3];
    for (int k = 0; k < 3; ++k) {
        e0[k] = __fsub_rn(v1[k], v0[k]);
        e1[k] = __fsub_rn(v2[k], v0[k]);
    }
    float a = dot_rn(e0, e0);
    float b = dot_rn(e0, e1);
    float cc = dot_rn(e1, e1);
    float det = __fsub_rn(__fmul_rn(a, cc), __fmul_rn(b, b));
    float det_s = (det > EPSF) ? det : 1.0f;
    float inv_det = 1.0f / det_s;
    float inv_a = 1.0f / ((a > EPSF) ? a : 1.0f);
    float inv_c = 1.0f / ((cc > EPSF) ? cc : 1.0f);
    float ee2 = __fsub_rn(__fadd_rn(a, cc), __fmul_rn(2.0f, b));
    float inv_ee2 = 1.0f / ((ee2 > EPSF) ? ee2 : 1.0f);
    float det2 = __fsub_rn(__fmul_rn(e0[0], e1[1]), __fmul_rn(e1[0], e0[1]));
    float det2_s = (fabsf(det2) > EPSF) ? det2 : 1.0f;
    float* o = fd + (size_t)f * FS;
    o[0] = v0[0]; o[1] = v0[1]; o[2] = v0[2];
    o[3] = e0[0]; o[4] = e0[1]; o[5] = e0[2];
    o[6] = e1[0]; o[7] = e1[1]; o[8] = e1[2];
    o[9] = a; o[10] = b; o[11] = cc;
    o[12] = det; o[13] = inv_det; o[14] = inv_a; o[15] = inv_c;
    o[16] = ee2; o[17] = inv_ee2; o[18] = det2; o[19] = det2_s;
}

// ---------------- kernel C: phi grid (8 face-chunks per point, LDS combine) ----------------
__global__ void __launch_bounds__(512) k_phi(const float* __restrict__ fd, int nf,
                                             int chunk, float* __restrict__ phi) {
    __shared__ float s_d2[512];
    __shared__ unsigned s_par[512];
    int lane = threadIdx.x & 63;
    int wv = __builtin_amdgcn_readfirstlane((int)(threadIdx.x >> 6));  // wave-uniform chunk id
    int n = blockIdx.x * 64 + lane;
    int gx = n & 31, gy = (n >> 5) & 31, gz = n >> 10;
    const float step = 2.0f / 31.0f;
    float px = __fadd_rn(-1.0f, __fmul_rn((float)gx, step));
    float py = __fadd_rn(-1.0f, __fmul_rn((float)gy, step));
    float pz = __fadd_rn(-1.0f, __fmul_rn((float)gz, step));

    float dmin = 3.402823466e38f;
    unsigned par = 0u;
    int f0 = wv * chunk;
    int f1 = min(nf, f0 + chunk);
    for (int f = f0; f < f1; ++f) {
        const float* q = fd + (size_t)f * FS;  // wave-uniform -> s_load
        float v0x = q[0], v0y = q[1], v0z = q[2];
        float e0x = q[3], e0y = q[4], e0z = q[5];
        float e1x = q[6], e1y = q[7], e1z = q[8];
        float a = q[9], b = q[10], cc = q[11];
        float det = q[12], inv_det = q[13], inv_a = q[14], inv_c = q[15];
        float ee2 = q[16], inv_ee2 = q[17], det2 = q[18], det2s = q[19];

        float wx = __fsub_rn(px, v0x), wy = __fsub_rn(py, v0y), wz = __fsub_rn(pz, v0z);
        // ---- distance path (continuous: default contraction fine) ----
        float ff = wx * wx + wy * wy + wz * wz;
        float de0 = wx * e0x + wy * e0y + wz * e0z;
        float de1 = wx * e1x + wy * e1y + wz * e1z;
        float u = (cc * de0 - b * de1) * inv_det;
        float v = (a * de1 - b * de0) * inv_det;
        bool inside = (u >= 0.0f) & (v >= 0.0f) & (u + v <= 1.0f) & (det > EPSF);
        float plane_d2 = ff - (u * de0 + v * de1);
        float t0 = fminf(fmaxf(de0 * inv_a, 0.0f), 1.0f);
        float d2_0 = ff + t0 * (t0 * a - 2.0f * de0);
        float t1 = fminf(fmaxf(de1 * inv_c, 0.0f), 1.0f);
        float d2_1 = ff + t1 * (t1 * cc - 2.0f * de1);
        float dot2 = de1 - de0 - (b - a);
        float w1sq = ff - 2.0f * de0 + a;
        float t2 = fminf(fmaxf(dot2 * inv_ee2, 0.0f), 1.0f);
        float d2_2 = w1sq + t2 * (t2 * ee2 - 2.0f * dot2);
        float ed2 = fminf(fminf(d2_0, d2_1), d2_2);
        float d2 = inside ? plane_d2 : ed2;
        dmin = fminf(dmin, fmaxf(d2, 0.0f));
        // ---- ray parity (discontinuous: replicate ref op order exactly) ----
        float u2n = __fsub_rn(__fmul_rn(wx, e1y), __fmul_rn(wy, e1x));
        float v2n = __fsub_rn(__fmul_rn(e0x, wy), __fmul_rn(e0y, wx));
        float u2 = __fdiv_rn(u2n, det2s);
        float v2 = __fdiv_rn(v2n, det2s);
        bool in2d = (u2 >= 0.0f) & (v2 >= 0.0f) & (__fadd_rn(u2, v2) <= 1.0f) &
                    (fabsf(det2) > EPSF);
        float zint = __fadd_rn(__fadd_rn(v0z, __fmul_rn(u2, e0z)), __fmul_rn(v2, e1z));
        par ^= (in2d && (zint > pz)) ? 1u : 0u;
    }
    s_d2[wv * 64 + lane] = dmin;
    s_par[wv * 64 + lane] = par;
    __syncthreads();
    if (threadIdx.x < 64) {
        for (int r = 1; r < 8; ++r) {
            dmin = fminf(dmin, s_d2[r * 64 + lane]);
            par ^= s_par[r * 64 + lane];
        }
        float dist = sqrtf(dmin);
        phi[n] = (par & 1u) ? dist : 0.0f;
    }
}

// ---------------- kernel D: trilinear sample + sum^2 + gate ----------------
__global__ void k_sample(const float* __restrict__ ov, int no,
                         const float* __restrict__ phi, const float* __restrict__ hdr,
                         float* __restrict__ out) {
    __shared__ float sred[256];
    int t = threadIdx.x;
    float cx = hdr[0], cy = hdr[1], cz = hdr[2], sc = hdr[3], ovl = hdr[4];
    float acc = 0.0f;
    for (int j = t; j < no; j += 256) {
        float qx = __fdiv_rn(__fsub_rn(ov[3 * j + 0], cx), sc);
        float qy = __fdiv_rn(__fsub_rn(ov[3 * j + 1], cy), sc);
        float qz = __fdiv_rn(__fsub_rn(ov[3 * j + 2], cz), sc);
        float fx = __fmul_rn(__fmul_rn(__fadd_rn(qx, 1.0f), 0.5f), 31.0f);
        float fy = __fmul_rn(__fmul_rn(__fadd_rn(qy, 1.0f), 0.5f), 31.0f);
        float fz = __fmul_rn(__fmul_rn(__fadd_rn(qz, 1.0f), 0.5f), 31.0f);
        float flx = floorf(fx), fly = floorf(fy), flz = floorf(fz);
        int ix0 = (int)flx, iy0 = (int)fly, iz0 = (int)flz;
        float w1x = __fsub_rn(fx, flx), w0x = __fsub_rn(1.0f, w1x);
        float w1y = __fsub_rn(fy, fly), w0y = __fsub_rn(1.0f, w1y);
        float w1z = __fsub_rn(fz, flz), w0z = __fsub_rn(1.0f, w1z);
        for (int dz = 0; dz < 2; ++dz)
            for (int dy = 0; dy < 2; ++dy)
                for (int dx = 0; dx < 2; ++dx) {
                    int ix = ix0 + dx, iy = iy0 + dy, iz = iz0 + dz;
                    bool valid = (ix >= 0) & (ix < GN) & (iy >= 0) & (iy < GN) &
                                 (iz >= 0) & (iz < GN);
                    if (valid) {
                        float val = phi[(iz * GN + iy) * GN + ix];
                        float wgt = __fmul_rn(__fmul_rn(dx ? w1x : w0x, dy ? w1y : w0y),
                                              dz ? w1z : w0z);
                        acc = __fadd_rn(acc, __fmul_rn(val, wgt));
                    }
                }
    }
    sred[t] = acc;
    __syncthreads();
    for (int s = 128; s > 0; s >>= 1) {
        if (t < s) sred[t] += sred[t + s];
        __syncthreads();
    }
    if (t == 0) {
        float S = sred[0];
        float loss = __fmul_rn(S, S);
        out[0] = (ovl != 0.0f) ? loss : 0.0f;
    }
}

extern "C" void kernel_launch(void* const* d_in, const int* in_sizes, int n_in,
                              void* d_out, int out_size, void* d_ws, size_t ws_size,
                              hipStream_t stream) {
    const float* hv = (const float*)d_in[0];
    const float* ov = (const float*)d_in[1];
    const int* faces = (const int*)d_in[2];
    int nh = in_sizes[0] / 3;
    int no = in_sizes[1] / 3;
    int nf = in_sizes[2] / 3;

    float* ws = (float*)d_ws;
    float* hdr = ws;                       // 32 floats
    float* fd = ws + 32;                   // nf * FS floats
    float* phi = fd + (size_t)nf * FS;     // 32768 floats
    int chunk = (nf + 7) / 8;

    k_setup<<<1, 256, 0, stream>>>(hv, nh, ov, no, hdr);
    k_faces<<<(nf + 255) / 256, 256, 0, stream>>>(hv, faces, nf, hdr, fd);
    k_phi<<<NPTS / 64, 512, 0, stream>>>(fd, nf, chunk, phi);
    k_sample<<<1, 256, 0, stream>>>(ov, no, phi, hdr, (float*)d_out);
}

// Round 2
// 222.242 us; speedup vs baseline: 1.1325x; 1.1325x over previous
//
#include <hip/hip_runtime.h>

#define EPSF 1e-12f
#define GN 32
#define NPTS (GN * GN * GN)
#define FS 24   // floats per precomputed face record (padded for aligned s_loads)

// ---------------- kernel A: fused bbox/center/scale + per-face precompute ----------------
__device__ __forceinline__ float dot_rn(const float* x, const float* y) {
    return __fadd_rn(__fadd_rn(__fmul_rn(x[0], y[0]), __fmul_rn(x[1], y[1])),
                     __fmul_rn(x[2], y[2]));
}

__global__ void k_prep(const float* __restrict__ hv, int nh,
                       const float* __restrict__ ov, int no,
                       const int* __restrict__ faces, int nf,
                       float* __restrict__ hdr, float* __restrict__ fd) {
    __shared__ float sred[256];
    __shared__ float s_hdr[5];
    int t = threadIdx.x;
    // ---- phase 1: bboxes ----
    float hmin[3] = { INFINITY, INFINITY, INFINITY };
    float hmax[3] = { -INFINITY, -INFINITY, -INFINITY };
    float omin[3] = { INFINITY, INFINITY, INFINITY };
    float omax[3] = { -INFINITY, -INFINITY, -INFINITY };
    for (int i = t; i < nh; i += 256)
        for (int k = 0; k < 3; ++k) {
            float v = hv[3 * i + k];
            hmin[k] = fminf(hmin[k], v);
            hmax[k] = fmaxf(hmax[k], v);
        }
    for (int i = t; i < no; i += 256)
        for (int k = 0; k < 3; ++k) {
            float v = ov[3 * i + k];
            omin[k] = fminf(omin[k], v);
            omax[k] = fmaxf(omax[k], v);
        }
    float vals[12] = { hmin[0], hmin[1], hmin[2], hmax[0], hmax[1], hmax[2],
                       omin[0], omin[1], omin[2], omax[0], omax[1], omax[2] };
    float red[12];
    for (int c = 0; c < 12; ++c) {
        bool ismin = (c < 3) || (c >= 6 && c < 9);
        sred[t] = vals[c];
        __syncthreads();
        for (int s = 128; s > 0; s >>= 1) {
            if (t < s) sred[t] = ismin ? fminf(sred[t], sred[t + s])
                                       : fmaxf(sred[t], sred[t + s]);
            __syncthreads();
        }
        red[c] = sred[0];
        __syncthreads();
    }
    if (t == 0) {
        bool ovl = true;
        for (int k = 0; k < 3; ++k)
            ovl = ovl && (red[k] <= red[9 + k]) && (red[6 + k] <= red[3 + k]);
        float ext0 = __fsub_rn(red[3], red[0]);
        float ext1 = __fsub_rn(red[4], red[1]);
        float ext2 = __fsub_rn(red[5], red[2]);
        float m = fmaxf(ext0, fmaxf(ext1, ext2));
        s_hdr[0] = __fmul_rn(0.5f, __fadd_rn(red[0], red[3]));   // center
        s_hdr[1] = __fmul_rn(0.5f, __fadd_rn(red[1], red[4]));
        s_hdr[2] = __fmul_rn(0.5f, __fadd_rn(red[2], red[5]));
        s_hdr[3] = __fmul_rn(0.6f, m);                            // scale
        s_hdr[4] = ovl ? 1.0f : 0.0f;                             // overlap
        for (int k = 0; k < 5; ++k) hdr[k] = s_hdr[k];
    }
    __syncthreads();
    // ---- phase 2: face records ----
    float c0 = s_hdr[0], c1 = s_hdr[1], c2 = s_hdr[2], sc = s_hdr[3];
    for (int f = t; f < nf; f += 256) {
        int ia = faces[3 * f + 0], ib = faces[3 * f + 1], ic = faces[3 * f + 2];
        float v0[3], v1[3], v2[3];
        for (int k = 0; k < 3; ++k) {
            float cen = (k == 0) ? c0 : ((k == 1) ? c1 : c2);
            v0[k] = __fdiv_rn(__fsub_rn(hv[3 * ia + k], cen), sc);
            v1[k] = __fdiv_rn(__fsub_rn(hv[3 * ib + k], cen), sc);
            v2[k] = __fdiv_rn(__fsub_rn(hv[3 * ic + k], cen), sc);
        }
        float e0[3], e1[3];
        for (int k = 0; k < 3; ++k) {
            e0[k] = __fsub_rn(v1[k], v0[k]);
            e1[k] = __fsub_rn(v2[k], v0[k]);
        }
        float a = dot_rn(e0, e0);
        float b = dot_rn(e0, e1);
        float cc = dot_rn(e1, e1);
        float det = __fsub_rn(__fmul_rn(a, cc), __fmul_rn(b, b));
        float det_s = (det > EPSF) ? det : 1.0f;
        float inv_det = 1.0f / det_s;
        float inv_a = 1.0f / ((a > EPSF) ? a : 1.0f);
        float inv_c = 1.0f / ((cc > EPSF) ? cc : 1.0f);
        float ee2 = __fsub_rn(__fadd_rn(a, cc), __fmul_rn(2.0f, b));
        float inv_ee2 = 1.0f / ((ee2 > EPSF) ? ee2 : 1.0f);
        float det2 = __fsub_rn(__fmul_rn(e0[0], e1[1]), __fmul_rn(e1[0], e0[1]));
        float det2_s = (fabsf(det2) > EPSF) ? det2 : 1.0f;
        float inv_det2s = 1.0f / det2_s;   // correctly-rounded, hoisted out of hot loop
        float* o = fd + (size_t)f * FS;
        o[0] = v0[0]; o[1] = v0[1]; o[2] = v0[2];
        o[3] = e0[0]; o[4] = e0[1]; o[5] = e0[2];
        o[6] = e1[0]; o[7] = e1[1]; o[8] = e1[2];
        o[9] = a; o[10] = b; o[11] = cc;
        o[12] = det; o[13] = inv_det; o[14] = inv_a; o[15] = inv_c;
        o[16] = ee2; o[17] = inv_ee2; o[18] = det2; o[19] = inv_det2s;
        o[20] = 0.f; o[21] = 0.f; o[22] = 0.f; o[23] = 0.f;
    }
}

// ---------------- kernel B: phi grid (16 face-chunks per point, LDS combine) ----------------
__global__ void __launch_bounds__(1024) k_phi(const float* __restrict__ fd, int nf,
                                              int chunk, float* __restrict__ phi) {
    __shared__ float s_d2[1024];
    __shared__ unsigned s_par[1024];
    int lane = threadIdx.x & 63;
    int wv = __builtin_amdgcn_readfirstlane((int)(threadIdx.x >> 6));  // wave-uniform chunk id
    int n = blockIdx.x * 64 + lane;
    int gx = n & 31, gy = (n >> 5) & 31, gz = n >> 10;
    const float step = 2.0f / 31.0f;
    float px = __fadd_rn(-1.0f, __fmul_rn((float)gx, step));
    float py = __fadd_rn(-1.0f, __fmul_rn((float)gy, step));
    float pz = __fadd_rn(-1.0f, __fmul_rn((float)gz, step));

    float dmin = 3.402823466e38f;
    unsigned par = 0u;
    int f0 = wv * chunk;
    int f1 = min(nf, f0 + chunk);
    for (int f = f0; f < f1; ++f) {
        const float* q = fd + (size_t)f * FS;  // wave-uniform -> s_load
        float v0x = q[0], v0y = q[1], v0z = q[2];
        float e0x = q[3], e0y = q[4], e0z = q[5];
        float e1x = q[6], e1y = q[7], e1z = q[8];
        float a = q[9], b = q[10], cc = q[11];
        float det = q[12], inv_det = q[13], inv_a = q[14], inv_c = q[15];
        float ee2 = q[16], inv_ee2 = q[17], det2 = q[18], inv_det2s = q[19];

        float wx = __fsub_rn(px, v0x), wy = __fsub_rn(py, v0y), wz = __fsub_rn(pz, v0z);
        // ---- distance path (continuous: default contraction fine) ----
        float ff = wx * wx + wy * wy + wz * wz;
        float de0 = wx * e0x + wy * e0y + wz * e0z;
        float de1 = wx * e1x + wy * e1y + wz * e1z;
        float u = (cc * de0 - b * de1) * inv_det;
        float v = (a * de1 - b * de0) * inv_det;
        bool inside = (u >= 0.0f) & (v >= 0.0f) & (u + v <= 1.0f) & (det > EPSF);
        float plane_d2 = ff - (u * de0 + v * de1);
        float t0 = fminf(fmaxf(de0 * inv_a, 0.0f), 1.0f);
        float d2_0 = ff + t0 * (t0 * a - 2.0f * de0);
        float t1 = fminf(fmaxf(de1 * inv_c, 0.0f), 1.0f);
        float d2_1 = ff + t1 * (t1 * cc - 2.0f * de1);
        float dot2 = de1 - de0 - (b - a);
        float w1sq = ff - 2.0f * de0 + a;
        float t2 = fminf(fmaxf(dot2 * inv_ee2, 0.0f), 1.0f);
        float d2_2 = w1sq + t2 * (t2 * ee2 - 2.0f * dot2);
        float ed2 = fminf(fminf(d2_0, d2_1), d2_2);
        float d2 = inside ? plane_d2 : ed2;
        dmin = fminf(dmin, fmaxf(d2, 0.0f));
        // ---- ray parity (reciprocal-mul; sign tests exact, boundary tests ~1.5ulp) ----
        float u2n = __fsub_rn(__fmul_rn(wx, e1y), __fmul_rn(wy, e1x));
        float v2n = __fsub_rn(__fmul_rn(e0x, wy), __fmul_rn(e0y, wx));
        float u2 = __fmul_rn(u2n, inv_det2s);
        float v2 = __fmul_rn(v2n, inv_det2s);
        bool in2d = (u2 >= 0.0f) & (v2 >= 0.0f) & (__fadd_rn(u2, v2) <= 1.0f) &
                    (fabsf(det2) > EPSF);
        float zint = __fadd_rn(__fadd_rn(v0z, __fmul_rn(u2, e0z)), __fmul_rn(v2, e1z));
        par ^= (in2d && (zint > pz)) ? 1u : 0u;
    }
    s_d2[wv * 64 + lane] = dmin;
    s_par[wv * 64 + lane] = par;
    __syncthreads();
    if (threadIdx.x < 64) {
        for (int r = 1; r < 16; ++r) {
            dmin = fminf(dmin, s_d2[r * 64 + lane]);
            par ^= s_par[r * 64 + lane];
        }
        float dist = sqrtf(dmin);
        phi[n] = (par & 1u) ? dist : 0.0f;
    }
}

// ---------------- kernel C: trilinear sample + sum^2 + gate ----------------
__global__ void k_sample(const float* __restrict__ ov, int no,
                         const float* __restrict__ phi, const float* __restrict__ hdr,
                         float* __restrict__ out) {
    __shared__ float sred[256];
    int t = threadIdx.x;
    float cx = hdr[0], cy = hdr[1], cz = hdr[2], sc = hdr[3], ovl = hdr[4];
    float acc = 0.0f;
    for (int j = t; j < no; j += 256) {
        float qx = __fdiv_rn(__fsub_rn(ov[3 * j + 0], cx), sc);
        float qy = __fdiv_rn(__fsub_rn(ov[3 * j + 1], cy), sc);
        float qz = __fdiv_rn(__fsub_rn(ov[3 * j + 2], cz), sc);
        float fx = __fmul_rn(__fmul_rn(__fadd_rn(qx, 1.0f), 0.5f), 31.0f);
        float fy = __fmul_rn(__fmul_rn(__fadd_rn(qy, 1.0f), 0.5f), 31.0f);
        float fz = __fmul_rn(__fmul_rn(__fadd_rn(qz, 1.0f), 0.5f), 31.0f);
        float flx = floorf(fx), fly = floorf(fy), flz = floorf(fz);
        int ix0 = (int)flx, iy0 = (int)fly, iz0 = (int)flz;
        float w1x = __fsub_rn(fx, flx), w0x = __fsub_rn(1.0f, w1x);
        float w1y = __fsub_rn(fy, fly), w0y = __fsub_rn(1.0f, w1y);
        float w1z = __fsub_rn(fz, flz), w0z = __fsub_rn(1.0f, w1z);
        for (int dz = 0; dz < 2; ++dz)
            for (int dy = 0; dy < 2; ++dy)
                for (int dx = 0; dx < 2; ++dx) {
                    int ix = ix0 + dx, iy = iy0 + dy, iz = iz0 + dz;
                    bool valid = (ix >= 0) & (ix < GN) & (iy >= 0) & (iy < GN) &
                                 (iz >= 0) & (iz < GN);
                    if (valid) {
                        float val = phi[(iz * GN + iy) * GN + ix];
                        float wgt = __fmul_rn(__fmul_rn(dx ? w1x : w0x, dy ? w1y : w0y),
                                              dz ? w1z : w0z);
                        acc = __fadd_rn(acc, __fmul_rn(val, wgt));
                    }
                }
    }
    sred[t] = acc;
    __syncthreads();
    for (int s = 128; s > 0; s >>= 1) {
        if (t < s) sred[t] += sred[t + s];
        __syncthreads();
    }
    if (t == 0) {
        float S = sred[0];
        float loss = __fmul_rn(S, S);
        out[0] = (ovl != 0.0f) ? loss : 0.0f;
    }
}

extern "C" void kernel_launch(void* const* d_in, const int* in_sizes, int n_in,
                              void* d_out, int out_size, void* d_ws, size_t ws_size,
                              hipStream_t stream) {
    const float* hv = (const float*)d_in[0];
    const float* ov = (const float*)d_in[1];
    const int* faces = (const int*)d_in[2];
    int nh = in_sizes[0] / 3;
    int no = in_sizes[1] / 3;
    int nf = in_sizes[2] / 3;

    float* ws = (float*)d_ws;
    float* hdr = ws;                       // 32 floats
    float* fd = ws + 32;                   // nf * FS floats
    float* phi = fd + (size_t)nf * FS;     // 32768 floats
    int chunk = (nf + 15) / 16;

    k_prep<<<1, 256, 0, stream>>>(hv, nh, ov, no, faces, nf, hdr, fd);
    k_phi<<<NPTS / 64, 1024, 0, stream>>>(fd, nf, chunk, phi);
    k_sample<<<1, 256, 0, stream>>>(ov, no, phi, hdr, (float*)d_out);
}

// Round 4
// 214.309 us; speedup vs baseline: 1.1744x; 1.0370x over previous
//
#include <hip/hip_runtime.h>

#define EPSF 1e-12f
#define GN 32
#define NPTS (GN * GN * GN)
#define NCOL (GN * GN)
#define FS 20      // floats per face record
#define FSPLIT 16  // face-splits (blocks per column-group)
#define NCG 16     // column-groups of 64 columns

__device__ __forceinline__ float dot_rn(const float* x, const float* y) {
    return __fadd_rn(__fadd_rn(__fmul_rn(x[0], y[0]), __fmul_rn(x[1], y[1])),
                     __fmul_rn(x[2], y[2]));
}

// ---------------- kernel A: bbox/center/scale + face records + buffer init ----------------
__global__ void k_prep(const float* __restrict__ hv, int nh,
                       const float* __restrict__ ov, int no,
                       const int* __restrict__ faces, int nf,
                       float* __restrict__ hdr, float* __restrict__ fd,
                       unsigned* __restrict__ d2u, unsigned* __restrict__ parm) {
    __shared__ float sred[256];
    __shared__ float s_hdr[5];
    int t = threadIdx.x;
    // init combine buffers (separate dispatch guarantees ordering vs k_phi)
    for (int i = t; i < NPTS; i += 256) d2u[i] = 0x7f800000u;   // +inf bits
    for (int i = t; i < NCOL; i += 256) parm[i] = 0u;
    // ---- bboxes ----
    float hmin[3] = { INFINITY, INFINITY, INFINITY };
    float hmax[3] = { -INFINITY, -INFINITY, -INFINITY };
    float omin[3] = { INFINITY, INFINITY, INFINITY };
    float omax[3] = { -INFINITY, -INFINITY, -INFINITY };
    for (int i = t; i < nh; i += 256)
        for (int k = 0; k < 3; ++k) {
            float v = hv[3 * i + k];
            hmin[k] = fminf(hmin[k], v);
            hmax[k] = fmaxf(hmax[k], v);
        }
    for (int i = t; i < no; i += 256)
        for (int k = 0; k < 3; ++k) {
            float v = ov[3 * i + k];
            omin[k] = fminf(omin[k], v);
            omax[k] = fmaxf(omax[k], v);
        }
    float vals[12] = { hmin[0], hmin[1], hmin[2], hmax[0], hmax[1], hmax[2],
                       omin[0], omin[1], omin[2], omax[0], omax[1], omax[2] };
    float red[12];
    for (int c = 0; c < 12; ++c) {
        bool ismin = (c < 3) || (c >= 6 && c < 9);
        sred[t] = vals[c];
        __syncthreads();
        for (int s = 128; s > 0; s >>= 1) {
            if (t < s) sred[t] = ismin ? fminf(sred[t], sred[t + s])
                                       : fmaxf(sred[t], sred[t + s]);
            __syncthreads();
        }
        red[c] = sred[0];
        __syncthreads();
    }
    if (t == 0) {
        bool ovl = true;
        for (int k = 0; k < 3; ++k)
            ovl = ovl && (red[k] <= red[9 + k]) && (red[6 + k] <= red[3 + k]);
        float ext0 = __fsub_rn(red[3], red[0]);
        float ext1 = __fsub_rn(red[4], red[1]);
        float ext2 = __fsub_rn(red[5], red[2]);
        float m = fmaxf(ext0, fmaxf(ext1, ext2));
        s_hdr[0] = __fmul_rn(0.5f, __fadd_rn(red[0], red[3]));
        s_hdr[1] = __fmul_rn(0.5f, __fadd_rn(red[1], red[4]));
        s_hdr[2] = __fmul_rn(0.5f, __fadd_rn(red[2], red[5]));
        s_hdr[3] = __fmul_rn(0.6f, m);
        s_hdr[4] = ovl ? 1.0f : 0.0f;
        for (int k = 0; k < 5; ++k) hdr[k] = s_hdr[k];
    }
    __syncthreads();
    // ---- face records ----
    float c0 = s_hdr[0], c1 = s_hdr[1], c2 = s_hdr[2], sc = s_hdr[3];
    const float qnan = __int_as_float(0x7FC00000);
    for (int f = t; f < nf; f += 256) {
        int ia = faces[3 * f + 0], ib = faces[3 * f + 1], ic = faces[3 * f + 2];
        float v0[3], v1[3], v2[3];
        for (int k = 0; k < 3; ++k) {
            float cen = (k == 0) ? c0 : ((k == 1) ? c1 : c2);
            v0[k] = __fdiv_rn(__fsub_rn(hv[3 * ia + k], cen), sc);
            v1[k] = __fdiv_rn(__fsub_rn(hv[3 * ib + k], cen), sc);
            v2[k] = __fdiv_rn(__fsub_rn(hv[3 * ic + k], cen), sc);
        }
        float e0[3], e1[3];
        for (int k = 0; k < 3; ++k) {
            e0[k] = __fsub_rn(v1[k], v0[k]);
            e1[k] = __fsub_rn(v2[k], v0[k]);
        }
        float a = dot_rn(e0, e0);
        float b = dot_rn(e0, e1);
        float cc = dot_rn(e1, e1);
        float det = __fsub_rn(__fmul_rn(a, cc), __fmul_rn(b, b));
        // NaN-poisoned reciprocals: NaN comparisons are false -> reference's
        // forced-false inside_tri / in2d for degenerate faces.
        float inv_det = (det > EPSF) ? (1.0f / det) : qnan;
        float inv_a = 1.0f / ((a > EPSF) ? a : 1.0f);
        float inv_c = 1.0f / ((cc > EPSF) ? cc : 1.0f);
        float ee2 = __fsub_rn(__fadd_rn(a, cc), __fmul_rn(2.0f, b));
        float inv_ee2 = 1.0f / ((ee2 > EPSF) ? ee2 : 1.0f);
        float det2 = __fsub_rn(__fmul_rn(e0[0], e1[1]), __fmul_rn(e1[0], e0[1]));
        float inv_det2s = (fabsf(det2) > EPSF) ? (1.0f / det2) : qnan;
        float* o = fd + (size_t)f * FS;
        o[0] = v0[0]; o[1] = v0[1]; o[2] = v0[2];
        o[3] = e0[0]; o[4] = e0[1]; o[5] = e0[2];
        o[6] = e1[0]; o[7] = e1[1]; o[8] = e1[2];
        o[9] = a; o[10] = b; o[11] = cc;
        o[12] = inv_det; o[13] = inv_a; o[14] = inv_c;
        o[15] = ee2; o[16] = inv_ee2; o[17] = inv_det2s;
        o[18] = __fsub_rn(b, a); o[19] = 0.f;
    }
}

// ---------------- kernel B: per-column phi (z folded), atomic combine ----------------
// block = (column-group cg: 64 columns) x (face-split fs). 16 waves split fs's faces.
// Each lane owns one (x,y) column over all 32 z. Parity terms are z-invariant:
// computed once per (face, column); z-mask derived by exact binary search on the
// identical pz_k values -> parity bit-exact vs per-z comparison.
__global__ void __launch_bounds__(1024) k_phi(const float* __restrict__ fd, int nf,
                                              unsigned* __restrict__ d2u,
                                              unsigned* __restrict__ parm) {
    __shared__ unsigned s_d2[2048];
    __shared__ unsigned s_pm[64];
    int t = threadIdx.x, lane = t & 63, wv = t >> 6;
    int fs = blockIdx.x >> 4;   // consecutive blocks share face range (L2-friendly)
    int cg = blockIdx.x & 15;
    const float step = 2.0f / 31.0f;

    for (int i = t; i < 2048; i += 1024) s_d2[i] = 0x7f800000u;
    if (t < 64) s_pm[t] = 0u;
    __syncthreads();

    int col = cg * 64 + lane;           // global column id = gy*32+gx
    int gx = col & 31, gy = col >> 5;
    float px = __fadd_rn(-1.0f, __fmul_rn((float)gx, step));
    float py = __fadd_rn(-1.0f, __fmul_rn((float)gy, step));

    int chunkB = (nf + FSPLIT - 1) / FSPLIT;
    int f0B = fs * chunkB;
    int f1B = min(nf, f0B + chunkB);
    int cw = (chunkB + 15) >> 4;
    int f0 = __builtin_amdgcn_readfirstlane(f0B + wv * cw);
    int f1 = __builtin_amdgcn_readfirstlane(min(f1B, f0B + wv * cw + cw));

    float dmin[32];
#pragma unroll
    for (int k = 0; k < 32; ++k) dmin[k] = 3.402823466e38f;
    unsigned cmask = 0u;

    for (int f = f0; f < f1; ++f) {
        const float* q = fd + (size_t)f * FS;  // wave-uniform -> s_load
        float v0x = q[0], v0y = q[1], v0z = q[2];
        float e0x = q[3], e0y = q[4], e0z = q[5];
        float e1x = q[6], e1y = q[7], e1z = q[8];
        float a = q[9], b = q[10], cc = q[11];
        float inv_det = q[12], inv_a = q[13], inv_c = q[14];
        float ee2 = q[15], inv_ee2 = q[16], inv_det2s = q[17];
        float bma = q[18];

        float wx = __fsub_rn(px, v0x), wy = __fsub_rn(py, v0y);
        float ffxy = wx * wx + wy * wy;
        float de0xy = wx * e0x + wy * e0y;
        float de1xy = wx * e1x + wy * e1y;

        // ---- parity: z-invariant part, bit-identical to R2's per-z path ----
        float u2n = __fsub_rn(__fmul_rn(wx, e1y), __fmul_rn(wy, e1x));
        float v2n = __fsub_rn(__fmul_rn(e0x, wy), __fmul_rn(e0y, wx));
        float u2 = __fmul_rn(u2n, inv_det2s);
        float v2 = __fmul_rn(v2n, inv_det2s);
        bool in2d = (u2 >= 0.0f) & (v2 >= 0.0f) & (__fadd_rn(u2, v2) <= 1.0f);
        float zint = __fadd_rn(__fadd_rn(v0z, __fmul_rn(u2, e0z)), __fmul_rn(v2, e1z));
        // c = #{k in [0,32): zint > pz_k}, exact compares on identical pz values
        int c = 0;
        {
            float p;
            p = __fadd_rn(-1.0f, __fmul_rn((float)(15), step));      if (zint > p) c = 16;
            p = __fadd_rn(-1.0f, __fmul_rn((float)(c + 7), step));   if (zint > p) c += 8;
            p = __fadd_rn(-1.0f, __fmul_rn((float)(c + 3), step));   if (zint > p) c += 4;
            p = __fadd_rn(-1.0f, __fmul_rn((float)(c + 1), step));   if (zint > p) c += 2;
            p = __fadd_rn(-1.0f, __fmul_rn((float)(c), step));       if (zint > p) c += 1;
            p = __fadd_rn(-1.0f, __fmul_rn((float)(c), step));       if (zint > p) c += 1;
        }
        unsigned mask = (c == 0) ? 0u : (0xffffffffu >> (32 - c));
        cmask ^= in2d ? mask : 0u;

        // ---- distance: unrolled z loop, wz from exact pz_k constants ----
#pragma unroll
        for (int k = 0; k < 32; ++k) {
            const float pzk = -1.0f + (float)k * (2.0f / 31.0f);  // folded, == __fadd_rn form
            float wz = __fsub_rn(pzk, v0z);
            float ff = fmaf(wz, wz, ffxy);
            float de0 = fmaf(wz, e0z, de0xy);
            float de1 = fmaf(wz, e1z, de1xy);
            float u = (cc * de0 - b * de1) * inv_det;
            float v = (a * de1 - b * de0) * inv_det;
            bool inside = (u >= 0.0f) & (v >= 0.0f) & (u + v <= 1.0f);  // NaN->false
            float plane_d2 = ff - (u * de0 + v * de1);
            float t0 = fminf(fmaxf(de0 * inv_a, 0.0f), 1.0f);
            float d2_0 = ff + t0 * (t0 * a - 2.0f * de0);
            float t1 = fminf(fmaxf(de1 * inv_c, 0.0f), 1.0f);
            float d2_1 = ff + t1 * (t1 * cc - 2.0f * de1);
            float dot2 = (de1 - de0) - bma;
            float w1sq = ff - 2.0f * de0 + a;
            float t2 = fminf(fmaxf(dot2 * inv_ee2, 0.0f), 1.0f);
            float d2_2 = w1sq + t2 * (t2 * ee2 - 2.0f * dot2);
            float ed2 = fminf(fminf(d2_0, d2_1), d2_2);
            float d2 = inside ? plane_d2 : ed2;
            dmin[k] = fminf(dmin[k], fmaxf(d2, 0.0f));
        }
    }

    // ---- combine: 16 wave-partials -> block partial (LDS), -> global atomics ----
#pragma unroll
    for (int k = 0; k < 32; ++k)
        atomicMin(&s_d2[k * 64 + lane], __float_as_uint(dmin[k]));
    atomicXor(&s_pm[lane], cmask);
    __syncthreads();
    for (int i = t; i < 2048; i += 1024) {
        int k = i >> 6, ln = i & 63;
        atomicMin(&d2u[k * NCOL + cg * 64 + ln], s_d2[i]);
    }
    if (t < 64) atomicXor(&parm[cg * 64 + t], s_pm[t]);
}

// ---------------- kernel C: trilinear sample from (d2u, parm) + sum^2 + gate ----------------
__global__ void k_sample(const float* __restrict__ ov, int no,
                         const unsigned* __restrict__ d2u,
                         const unsigned* __restrict__ parm,
                         const float* __restrict__ hdr,
                         float* __restrict__ out) {
    __shared__ float sred[256];
    int t = threadIdx.x;
    float cx = hdr[0], cy = hdr[1], cz = hdr[2], sc = hdr[3], ovl = hdr[4];
    float acc = 0.0f;
    for (int j = t; j < no; j += 256) {
        float qx = __fdiv_rn(__fsub_rn(ov[3 * j + 0], cx), sc);
        float qy = __fdiv_rn(__fsub_rn(ov[3 * j + 1], cy), sc);
        float qz = __fdiv_rn(__fsub_rn(ov[3 * j + 2], cz), sc);
        float fx = __fmul_rn(__fmul_rn(__fadd_rn(qx, 1.0f), 0.5f), 31.0f);
        float fy = __fmul_rn(__fmul_rn(__fadd_rn(qy, 1.0f), 0.5f), 31.0f);
        float fz = __fmul_rn(__fmul_rn(__fadd_rn(qz, 1.0f), 0.5f), 31.0f);
        float flx = floorf(fx), fly = floorf(fy), flz = floorf(fz);
        int ix0 = (int)flx, iy0 = (int)fly, iz0 = (int)flz;
        float w1x = __fsub_rn(fx, flx), w0x = __fsub_rn(1.0f, w1x);
        float w1y = __fsub_rn(fy, fly), w0y = __fsub_rn(1.0f, w1y);
        float w1z = __fsub_rn(fz, flz), w0z = __fsub_rn(1.0f, w1z);
        for (int dz = 0; dz < 2; ++dz)
            for (int dy = 0; dy < 2; ++dy)
                for (int dx = 0; dx < 2; ++dx) {
                    int ix = ix0 + dx, iy = iy0 + dy, iz = iz0 + dz;
                    bool valid = (ix >= 0) & (ix < GN) & (iy >= 0) & (iy < GN) &
                                 (iz >= 0) & (iz < GN);
                    if (valid) {
                        unsigned pm = parm[iy * GN + ix];
                        float val = 0.0f;
                        if ((pm >> iz) & 1u)
                            val = sqrtf(__uint_as_float(d2u[(iz * GN + iy) * GN + ix]));
                        float wgt = __fmul_rn(__fmul_rn(dx ? w1x : w0x, dy ? w1y : w0y),
                                              dz ? w1z : w0z);
                        acc = __fadd_rn(acc, __fmul_rn(val, wgt));
                    }
                }
    }
    sred[t] = acc;
    __syncthreads();
    for (int s = 128; s > 0; s >>= 1) {
        if (t < s) sred[t] += sred[t + s];
        __syncthreads();
    }
    if (t == 0) {
        float S = sred[0];
        float loss = __fmul_rn(S, S);
        out[0] = (ovl != 0.0f) ? loss : 0.0f;
    }
}

extern "C" void kernel_launch(void* const* d_in, const int* in_sizes, int n_in,
                              void* d_out, int out_size, void* d_ws, size_t ws_size,
                              hipStream_t stream) {
    const float* hv = (const float*)d_in[0];
    const float* ov = (const float*)d_in[1];
    const int* faces = (const int*)d_in[2];
    int nh = in_sizes[0] / 3;
    int no = in_sizes[1] / 3;
    int nf = in_sizes[2] / 3;

    float* ws = (float*)d_ws;
    float* hdr = ws;                                   // 32 floats
    float* fd = ws + 32;                               // nf * FS floats
    unsigned* d2u = (unsigned*)(fd + (size_t)nf * FS); // NPTS u32
    unsigned* parm = d2u + NPTS;                       // NCOL u32

    k_prep<<<1, 256, 0, stream>>>(hv, nh, ov, no, faces, nf, hdr, fd, d2u, parm);
    k_phi<<<NCG * FSPLIT, 1024, 0, stream>>>(fd, nf, d2u, parm);
    k_sample<<<1, 256, 0, stream>>>(ov, no, d2u, parm, hdr, (float*)d_out);
}

// Round 5
// 200.970 us; speedup vs baseline: 1.2523x; 1.0664x over previous
//
#include <hip/hip_runtime.h>

#define EPSF 1e-12f
#define GN 32
#define NPTS (GN * GN * GN)
#define NCOL (GN * GN)
#define FSPLIT 16   // face-splits
#define NCG 16      // column-groups of 64 columns
#define NBLK (NCG * FSPLIT)
#define NTHR 1024
#define MAXCH 160   // max faces per split staged in LDS (nf up to 2560)

__device__ __forceinline__ float dot_rn(const float* x, const float* y) {
    return __fadd_rn(__fadd_rn(__fmul_rn(x[0], y[0]), __fmul_rn(x[1], y[1])),
                     __fmul_rn(x[2], y[2]));
}
__device__ __forceinline__ float wmin64(float v) {
    for (int o = 32; o > 0; o >>= 1) v = fminf(v, __shfl_xor(v, o));
    return v;
}
__device__ __forceinline__ float wmax64(float v) {
    for (int o = 32; o > 0; o >>= 1) v = fmaxf(v, __shfl_xor(v, o));
    return v;
}
__device__ __forceinline__ float wsum64(float v) {
    for (int o = 32; o > 0; o >>= 1) v += __shfl_xor(v, o);
    return v;
}

// ws layout (memset to 0xFF before launch): [d2u NPTS u32][parm NCOL u32][counter]
__global__ void __launch_bounds__(NTHR) k_all(
    const float* __restrict__ hv, int nh,
    const float* __restrict__ ov, int no,
    const int* __restrict__ faces, int nf,
    unsigned* __restrict__ d2u, unsigned* __restrict__ parm,
    unsigned* __restrict__ counter, float* __restrict__ out)
{
    __shared__ float s_fd[MAXCH * 20];
    __shared__ unsigned s_d2[2048];
    __shared__ unsigned s_pm[64];
    __shared__ float s_w[16][8];
    __shared__ float s_hdr[4];
    __shared__ float s_hb[6];
    __shared__ unsigned s_last;
    __shared__ float s_ovl;

    int t = threadIdx.x, lane = t & 63, wvid = t >> 6;
    int fs = blockIdx.x >> 4;   // face-split id
    int cg = blockIdx.x & 15;   // column-group id
    const float step = 2.0f / 31.0f;

    // ---------- phase A: human bbox -> center/scale (redundant per block) ----------
    {
        float mnx = INFINITY, mny = INFINITY, mnz = INFINITY;
        float mxx = -INFINITY, mxy = -INFINITY, mxz = -INFINITY;
        for (int i = t; i < nh; i += NTHR) {
            float x = hv[3 * i], y = hv[3 * i + 1], z = hv[3 * i + 2];
            mnx = fminf(mnx, x); mny = fminf(mny, y); mnz = fminf(mnz, z);
            mxx = fmaxf(mxx, x); mxy = fmaxf(mxy, y); mxz = fmaxf(mxz, z);
        }
        mnx = wmin64(mnx); mny = wmin64(mny); mnz = wmin64(mnz);
        mxx = wmax64(mxx); mxy = wmax64(mxy); mxz = wmax64(mxz);
        if (lane == 0) {
            s_w[wvid][0] = mnx; s_w[wvid][1] = mny; s_w[wvid][2] = mnz;
            s_w[wvid][3] = mxx; s_w[wvid][4] = mxy; s_w[wvid][5] = mxz;
        }
        __syncthreads();
        if (wvid == 0) {
            float a0 = (lane < 16) ? s_w[lane][0] : INFINITY;
            float a1 = (lane < 16) ? s_w[lane][1] : INFINITY;
            float a2 = (lane < 16) ? s_w[lane][2] : INFINITY;
            float a3 = (lane < 16) ? s_w[lane][3] : -INFINITY;
            float a4 = (lane < 16) ? s_w[lane][4] : -INFINITY;
            float a5 = (lane < 16) ? s_w[lane][5] : -INFINITY;
            a0 = wmin64(a0); a1 = wmin64(a1); a2 = wmin64(a2);
            a3 = wmax64(a3); a4 = wmax64(a4); a5 = wmax64(a5);
            if (lane == 0) {
                float e0 = __fsub_rn(a3, a0);
                float e1 = __fsub_rn(a4, a1);
                float e2 = __fsub_rn(a5, a2);
                float m = fmaxf(e0, fmaxf(e1, e2));
                s_hdr[0] = __fmul_rn(0.5f, __fadd_rn(a0, a3));
                s_hdr[1] = __fmul_rn(0.5f, __fadd_rn(a1, a4));
                s_hdr[2] = __fmul_rn(0.5f, __fadd_rn(a2, a5));
                s_hdr[3] = __fmul_rn(0.6f, m);
                s_hb[0] = a0; s_hb[1] = a1; s_hb[2] = a2;
                s_hb[3] = a3; s_hb[4] = a4; s_hb[5] = a5;
            }
        }
        __syncthreads();
    }
    float cx = s_hdr[0], cy = s_hdr[1], cz = s_hdr[2], sc = s_hdr[3];

    // ---------- phase B: this split's face records -> LDS ----------
    int chunkB = (nf + FSPLIT - 1) / FSPLIT;
    int f0B = fs * chunkB;
    int f1B = min(nf, f0B + chunkB);
    int nloc = f1B - f0B;
    const float qnan = __int_as_float(0x7FC00000);
    for (int i = t; i < nloc; i += NTHR) {
        int f = f0B + i;
        int ia = faces[3 * f + 0], ib = faces[3 * f + 1], ic = faces[3 * f + 2];
        float v0[3], v1[3], v2[3];
        for (int k = 0; k < 3; ++k) {
            float cen = (k == 0) ? cx : ((k == 1) ? cy : cz);
            v0[k] = __fdiv_rn(__fsub_rn(hv[3 * ia + k], cen), sc);
            v1[k] = __fdiv_rn(__fsub_rn(hv[3 * ib + k], cen), sc);
            v2[k] = __fdiv_rn(__fsub_rn(hv[3 * ic + k], cen), sc);
        }
        float e0[3], e1[3];
        for (int k = 0; k < 3; ++k) {
            e0[k] = __fsub_rn(v1[k], v0[k]);
            e1[k] = __fsub_rn(v2[k], v0[k]);
        }
        float a = dot_rn(e0, e0);
        float b = dot_rn(e0, e1);
        float cc = dot_rn(e1, e1);
        float det = __fsub_rn(__fmul_rn(a, cc), __fmul_rn(b, b));
        // NaN-poisoned reciprocals: NaN comparisons false -> reference's forced-false
        float inv_det = (det > EPSF) ? (1.0f / det) : qnan;
        float inv_a = 1.0f / ((a > EPSF) ? a : 1.0f);
        float inv_c = 1.0f / ((cc > EPSF) ? cc : 1.0f);
        float ee2 = __fsub_rn(__fadd_rn(a, cc), __fmul_rn(2.0f, b));
        float inv_ee2 = 1.0f / ((ee2 > EPSF) ? ee2 : 1.0f);
        float det2 = __fsub_rn(__fmul_rn(e0[0], e1[1]), __fmul_rn(e1[0], e0[1]));
        float inv_det2s = (fabsf(det2) > EPSF) ? (1.0f / det2) : qnan;
        float* o = s_fd + i * 20;
        o[0] = v0[0]; o[1] = v0[1]; o[2] = v0[2];
        o[3] = e0[0]; o[4] = e0[1]; o[5] = e0[2];
        o[6] = e1[0]; o[7] = e1[1]; o[8] = e1[2];
        o[9] = a; o[10] = b; o[11] = cc;
        o[12] = inv_det; o[13] = inv_a; o[14] = inv_c;
        o[15] = ee2; o[16] = inv_ee2; o[17] = inv_det2s;
        o[18] = __fsub_rn(b, a); o[19] = 0.f;
    }
    for (int i = t; i < 2048; i += NTHR) s_d2[i] = 0x7f800000u;
    if (t < 64) s_pm[t] = 0u;
    __syncthreads();

    // ---------- phase C: z-folded hot loop (bit-identical math to R4) ----------
    {
        int col = cg * 64 + lane;           // gy*32+gx
        int gx = col & 31, gy = col >> 5;
        float px = __fadd_rn(-1.0f, __fmul_rn((float)gx, step));
        float py = __fadd_rn(-1.0f, __fmul_rn((float)gy, step));

        int cw = (nloc + 15) >> 4;
        int i0 = __builtin_amdgcn_readfirstlane(wvid * cw);
        int i1 = __builtin_amdgcn_readfirstlane(min(nloc, wvid * cw + cw));

        float dmin[32];
#pragma unroll
        for (int k = 0; k < 32; ++k) dmin[k] = 3.402823466e38f;
        unsigned cmask = 0u;

        for (int i = i0; i < i1; ++i) {
            const float* q = s_fd + i * 20;   // wave-uniform -> ds_read broadcast
            float v0x = q[0], v0y = q[1], v0z = q[2];
            float e0x = q[3], e0y = q[4], e0z = q[5];
            float e1x = q[6], e1y = q[7], e1z = q[8];
            float a = q[9], b = q[10], cc = q[11];
            float inv_det = q[12], inv_a = q[13], inv_c = q[14];
            float ee2 = q[15], inv_ee2 = q[16], inv_det2s = q[17];
            float bma = q[18];

            float wx = __fsub_rn(px, v0x), wy = __fsub_rn(py, v0y);
            float ffxy = wx * wx + wy * wy;
            float de0xy = wx * e0x + wy * e0y;
            float de1xy = wx * e1x + wy * e1y;

            float u2n = __fsub_rn(__fmul_rn(wx, e1y), __fmul_rn(wy, e1x));
            float v2n = __fsub_rn(__fmul_rn(e0x, wy), __fmul_rn(e0y, wx));
            float u2 = __fmul_rn(u2n, inv_det2s);
            float v2 = __fmul_rn(v2n, inv_det2s);
            bool in2d = (u2 >= 0.0f) & (v2 >= 0.0f) & (__fadd_rn(u2, v2) <= 1.0f);
            float zint = __fadd_rn(__fadd_rn(v0z, __fmul_rn(u2, e0z)), __fmul_rn(v2, e1z));
            int c = 0;
            {
                float p;
                p = __fadd_rn(-1.0f, __fmul_rn((float)(15), step));      if (zint > p) c = 16;
                p = __fadd_rn(-1.0f, __fmul_rn((float)(c + 7), step));   if (zint > p) c += 8;
                p = __fadd_rn(-1.0f, __fmul_rn((float)(c + 3), step));   if (zint > p) c += 4;
                p = __fadd_rn(-1.0f, __fmul_rn((float)(c + 1), step));   if (zint > p) c += 2;
                p = __fadd_rn(-1.0f, __fmul_rn((float)(c), step));       if (zint > p) c += 1;
                p = __fadd_rn(-1.0f, __fmul_rn((float)(c), step));       if (zint > p) c += 1;
            }
            unsigned mask = (c == 0) ? 0u : (0xffffffffu >> (32 - c));
            cmask ^= in2d ? mask : 0u;

#pragma unroll
            for (int k = 0; k < 32; ++k) {
                const float pzk = -1.0f + (float)k * (2.0f / 31.0f);
                float wz = __fsub_rn(pzk, v0z);
                float ff = fmaf(wz, wz, ffxy);
                float de0 = fmaf(wz, e0z, de0xy);
                float de1 = fmaf(wz, e1z, de1xy);
                float u = (cc * de0 - b * de1) * inv_det;
                float v = (a * de1 - b * de0) * inv_det;
                bool inside = (u >= 0.0f) & (v >= 0.0f) & (u + v <= 1.0f);
                float plane_d2 = ff - (u * de0 + v * de1);
                float t0 = fminf(fmaxf(de0 * inv_a, 0.0f), 1.0f);
                float d2_0 = ff + t0 * (t0 * a - 2.0f * de0);
                float t1 = fminf(fmaxf(de1 * inv_c, 0.0f), 1.0f);
                float d2_1 = ff + t1 * (t1 * cc - 2.0f * de1);
                float dot2 = (de1 - de0) - bma;
                float w1sq = ff - 2.0f * de0 + a;
                float t2 = fminf(fmaxf(dot2 * inv_ee2, 0.0f), 1.0f);
                float d2_2 = w1sq + t2 * (t2 * ee2 - 2.0f * dot2);
                float ed2 = fminf(fminf(d2_0, d2_1), d2_2);
                float d2 = inside ? plane_d2 : ed2;
                dmin[k] = fminf(dmin[k], fmaxf(d2, 0.0f));
            }
        }

        // block combine (LDS), then device-scope atomics into ws buffers
#pragma unroll
        for (int k = 0; k < 32; ++k)
            atomicMin(&s_d2[k * 64 + lane], __float_as_uint(dmin[k]));
        atomicXor(&s_pm[lane], cmask);
        __syncthreads();
        for (int i = t; i < 2048; i += NTHR) {
            int k = i >> 6, ln = i & 63;
            atomicMin(&d2u[k * NCOL + cg * 64 + ln], s_d2[i]);
        }
        if (t < 64) atomicXor(&parm[cg * 64 + t], s_pm[t]);
    }

    // ---------- completion counter: last block finishes ----------
    __threadfence();
    __syncthreads();
    if (t == 0) {
        unsigned old = atomicAdd(counter, 1u);   // base 0xFFFFFFFF from memset
        s_last = (old == (unsigned)(NBLK - 2)) ? 1u : 0u;
    }
    __syncthreads();
    if (s_last == 0u) return;
    __threadfence();

    // ---------- finisher (one block): o-bbox + overlap + sample + loss ----------
    {
        float onx = INFINITY, ony = INFINITY, onz = INFINITY;
        float oxx = -INFINITY, oxy = -INFINITY, oxz = -INFINITY;
        for (int j = t; j < no; j += NTHR) {
            float x = ov[3 * j], y = ov[3 * j + 1], z = ov[3 * j + 2];
            onx = fminf(onx, x); ony = fminf(ony, y); onz = fminf(onz, z);
            oxx = fmaxf(oxx, x); oxy = fmaxf(oxy, y); oxz = fmaxf(oxz, z);
        }
        onx = wmin64(onx); ony = wmin64(ony); onz = wmin64(onz);
        oxx = wmax64(oxx); oxy = wmax64(oxy); oxz = wmax64(oxz);
        if (lane == 0) {
            s_w[wvid][0] = onx; s_w[wvid][1] = ony; s_w[wvid][2] = onz;
            s_w[wvid][3] = oxx; s_w[wvid][4] = oxy; s_w[wvid][5] = oxz;
        }
        __syncthreads();
        if (wvid == 0) {
            float a0 = (lane < 16) ? s_w[lane][0] : INFINITY;
            float a1 = (lane < 16) ? s_w[lane][1] : INFINITY;
            float a2 = (lane < 16) ? s_w[lane][2] : INFINITY;
            float a3 = (lane < 16) ? s_w[lane][3] : -INFINITY;
            float a4 = (lane < 16) ? s_w[lane][4] : -INFINITY;
            float a5 = (lane < 16) ? s_w[lane][5] : -INFINITY;
            a0 = wmin64(a0); a1 = wmin64(a1); a2 = wmin64(a2);
            a3 = wmax64(a3); a4 = wmax64(a4); a5 = wmax64(a5);
            if (lane == 0) {
                bool ovl = (s_hb[0] <= a3) && (s_hb[1] <= a4) && (s_hb[2] <= a5) &&
                           (a0 <= s_hb[3]) && (a1 <= s_hb[4]) && (a2 <= s_hb[5]);
                s_ovl = ovl ? 1.0f : 0.0f;
            }
        }
        __syncthreads();
        float acc = 0.0f;
        for (int j = t; j < no; j += NTHR) {
            float qx = __fdiv_rn(__fsub_rn(ov[3 * j + 0], cx), sc);
            float qy = __fdiv_rn(__fsub_rn(ov[3 * j + 1], cy), sc);
            float qz = __fdiv_rn(__fsub_rn(ov[3 * j + 2], cz), sc);
            float fx = __fmul_rn(__fmul_rn(__fadd_rn(qx, 1.0f), 0.5f), 31.0f);
            float fy = __fmul_rn(__fmul_rn(__fadd_rn(qy, 1.0f), 0.5f), 31.0f);
            float fz = __fmul_rn(__fmul_rn(__fadd_rn(qz, 1.0f), 0.5f), 31.0f);
            float flx = floorf(fx), fly = floorf(fy), flz = floorf(fz);
            int ix0 = (int)flx, iy0 = (int)fly, iz0 = (int)flz;
            float w1x = __fsub_rn(fx, flx), w0x = __fsub_rn(1.0f, w1x);
            float w1y = __fsub_rn(fy, fly), w0y = __fsub_rn(1.0f, w1y);
            float w1z = __fsub_rn(fz, flz), w0z = __fsub_rn(1.0f, w1z);
            for (int dz = 0; dz < 2; ++dz)
                for (int dy = 0; dy < 2; ++dy)
                    for (int dx = 0; dx < 2; ++dx) {
                        int ix = ix0 + dx, iy = iy0 + dy, iz = iz0 + dz;
                        bool valid = (ix >= 0) & (ix < GN) & (iy >= 0) & (iy < GN) &
                                     (iz >= 0) & (iz < GN);
                        if (valid) {
                            // agent-scope loads: coherent vs other XCDs' atomics
                            unsigned pmv = __hip_atomic_load(&parm[iy * GN + ix],
                                                __ATOMIC_RELAXED, __HIP_MEMORY_SCOPE_AGENT);
                            unsigned pm = pmv ^ 0xFFFFFFFFu;   // remove memset base
                            float val = 0.0f;
                            if ((pm >> iz) & 1u) {
                                unsigned du = __hip_atomic_load(&d2u[(iz * GN + iy) * GN + ix],
                                                __ATOMIC_RELAXED, __HIP_MEMORY_SCOPE_AGENT);
                                val = sqrtf(__uint_as_float(du));
                            }
                            float wgt = __fmul_rn(__fmul_rn(dx ? w1x : w0x, dy ? w1y : w0y),
                                                  dz ? w1z : w0z);
                            acc = __fadd_rn(acc, __fmul_rn(val, wgt));
                        }
                    }
        }
        acc = wsum64(acc);
        if (lane == 0) s_w[wvid][6] = acc;
        __syncthreads();
        if (wvid == 0) {
            float v = (lane < 16) ? s_w[lane][6] : 0.0f;
            v = wsum64(v);
            if (lane == 0) {
                float loss = __fmul_rn(v, v);
                out[0] = (s_ovl != 0.0f) ? loss : 0.0f;
            }
        }
    }
}

extern "C" void kernel_launch(void* const* d_in, const int* in_sizes, int n_in,
                              void* d_out, int out_size, void* d_ws, size_t ws_size,
                              hipStream_t stream) {
    const float* hv = (const float*)d_in[0];
    const float* ov = (const float*)d_in[1];
    const int* faces = (const int*)d_in[2];
    int nh = in_sizes[0] / 3;
    int no = in_sizes[1] / 3;
    int nf = in_sizes[2] / 3;

    unsigned* d2u = (unsigned*)d_ws;          // NPTS u32
    unsigned* parm = d2u + NPTS;              // NCOL u32
    unsigned* counter = parm + NCOL;          // 1 u32 (+pad)

    // one node: init d2u=UINT_MAX (atomicMin top), parm=0xFFFFFFFF (XOR base,
    // removed in finisher), counter=0xFFFFFFFF (add base; 256th old == 254)
    hipMemsetAsync(d_ws, 0xFF, (size_t)(NPTS + NCOL + 16) * 4, stream);
    k_all<<<NBLK, NTHR, 0, stream>>>(hv, nh, ov, no, faces, nf,
                                     d2u, parm, counter, (float*)d_out);
}

// Round 6
// 194.659 us; speedup vs baseline: 1.2929x; 1.0324x over previous
//
#include <hip/hip_runtime.h>

#define EPSF 1e-12f
#define GN 32
#define NPTS (GN * GN * GN)
#define NCOL (GN * GN)
#define FSPLIT 16   // face-splits
#define NCG 16      // column-groups of 64 columns
#define NBLK (NCG * FSPLIT)
#define NTHR 1024
#define MAXCH 160   // max faces per split staged in LDS (nf up to 2560)

__device__ __forceinline__ float dot_rn(const float* x, const float* y) {
    return __fadd_rn(__fadd_rn(__fmul_rn(x[0], y[0]), __fmul_rn(x[1], y[1])),
                     __fmul_rn(x[2], y[2]));
}
__device__ __forceinline__ float wmin64(float v) {
    for (int o = 32; o > 0; o >>= 1) v = fminf(v, __shfl_xor(v, o));
    return v;
}
__device__ __forceinline__ float wmax64(float v) {
    for (int o = 32; o > 0; o >>= 1) v = fmaxf(v, __shfl_xor(v, o));
    return v;
}
__device__ __forceinline__ float wsum64(float v) {
    for (int o = 32; o > 0; o >>= 1) v += __shfl_xor(v, o);
    return v;
}

// ws layout (memset to 0xFF before launch): [d2u NPTS u32][parm NCOL u32][counter]
// __launch_bounds__(1024,4): 1 block/CU target -> 128-VGPR budget so dmin[32]
// plus the 15 z-invariant face values stay in registers across the z-unroll
// (at 64 VGPRs the allocator re-issued ds_reads inside the loop -> R5's stalls).
__global__ void __launch_bounds__(NTHR, 4) k_all(
    const float* __restrict__ hv, int nh,
    const float* __restrict__ ov, int no,
    const int* __restrict__ faces, int nf,
    unsigned* __restrict__ d2u, unsigned* __restrict__ parm,
    unsigned* __restrict__ counter, float* __restrict__ out)
{
    __shared__ float s_fd[MAXCH * 20];
    __shared__ unsigned s_d2[2048];
    __shared__ unsigned s_pm[64];
    __shared__ float s_w[16][8];
    __shared__ float s_hdr[4];
    __shared__ float s_hb[6];
    __shared__ unsigned s_last;
    __shared__ float s_ovl;

    int t = threadIdx.x, lane = t & 63, wvid = t >> 6;
    int fs = blockIdx.x >> 4;   // face-split id
    int cg = blockIdx.x & 15;   // column-group id
    const float step = 2.0f / 31.0f;

    // ---------- phase A: human bbox -> center/scale (redundant per block) ----------
    {
        float mnx = INFINITY, mny = INFINITY, mnz = INFINITY;
        float mxx = -INFINITY, mxy = -INFINITY, mxz = -INFINITY;
        for (int i = t; i < nh; i += NTHR) {
            float x = hv[3 * i], y = hv[3 * i + 1], z = hv[3 * i + 2];
            mnx = fminf(mnx, x); mny = fminf(mny, y); mnz = fminf(mnz, z);
            mxx = fmaxf(mxx, x); mxy = fmaxf(mxy, y); mxz = fmaxf(mxz, z);
        }
        mnx = wmin64(mnx); mny = wmin64(mny); mnz = wmin64(mnz);
        mxx = wmax64(mxx); mxy = wmax64(mxy); mxz = wmax64(mxz);
        if (lane == 0) {
            s_w[wvid][0] = mnx; s_w[wvid][1] = mny; s_w[wvid][2] = mnz;
            s_w[wvid][3] = mxx; s_w[wvid][4] = mxy; s_w[wvid][5] = mxz;
        }
        __syncthreads();
        if (wvid == 0) {
            float a0 = (lane < 16) ? s_w[lane][0] : INFINITY;
            float a1 = (lane < 16) ? s_w[lane][1] : INFINITY;
            float a2 = (lane < 16) ? s_w[lane][2] : INFINITY;
            float a3 = (lane < 16) ? s_w[lane][3] : -INFINITY;
            float a4 = (lane < 16) ? s_w[lane][4] : -INFINITY;
            float a5 = (lane < 16) ? s_w[lane][5] : -INFINITY;
            a0 = wmin64(a0); a1 = wmin64(a1); a2 = wmin64(a2);
            a3 = wmax64(a3); a4 = wmax64(a4); a5 = wmax64(a5);
            if (lane == 0) {
                float e0 = __fsub_rn(a3, a0);
                float e1 = __fsub_rn(a4, a1);
                float e2 = __fsub_rn(a5, a2);
                float m = fmaxf(e0, fmaxf(e1, e2));
                s_hdr[0] = __fmul_rn(0.5f, __fadd_rn(a0, a3));
                s_hdr[1] = __fmul_rn(0.5f, __fadd_rn(a1, a4));
                s_hdr[2] = __fmul_rn(0.5f, __fadd_rn(a2, a5));
                s_hdr[3] = __fmul_rn(0.6f, m);
                s_hb[0] = a0; s_hb[1] = a1; s_hb[2] = a2;
                s_hb[3] = a3; s_hb[4] = a4; s_hb[5] = a5;
            }
        }
        __syncthreads();
    }
    float cx = s_hdr[0], cy = s_hdr[1], cz = s_hdr[2], sc = s_hdr[3];

    // ---------- phase B: this split's face records -> LDS ----------
    int chunkB = (nf + FSPLIT - 1) / FSPLIT;
    int f0B = fs * chunkB;
    int f1B = min(nf, f0B + chunkB);
    int nloc = f1B - f0B;
    const float qnan = __int_as_float(0x7FC00000);
    for (int i = t; i < nloc; i += NTHR) {
        int f = f0B + i;
        int ia = faces[3 * f + 0], ib = faces[3 * f + 1], ic = faces[3 * f + 2];
        float v0[3], v1[3], v2[3];
        for (int k = 0; k < 3; ++k) {
            float cen = (k == 0) ? cx : ((k == 1) ? cy : cz);
            v0[k] = __fdiv_rn(__fsub_rn(hv[3 * ia + k], cen), sc);
            v1[k] = __fdiv_rn(__fsub_rn(hv[3 * ib + k], cen), sc);
            v2[k] = __fdiv_rn(__fsub_rn(hv[3 * ic + k], cen), sc);
        }
        float e0[3], e1[3];
        for (int k = 0; k < 3; ++k) {
            e0[k] = __fsub_rn(v1[k], v0[k]);
            e1[k] = __fsub_rn(v2[k], v0[k]);
        }
        float a = dot_rn(e0, e0);
        float b = dot_rn(e0, e1);
        float cc = dot_rn(e1, e1);
        float det = __fsub_rn(__fmul_rn(a, cc), __fmul_rn(b, b));
        // NaN-poisoned reciprocals: NaN comparisons false -> reference's forced-false
        float inv_det = (det > EPSF) ? (1.0f / det) : qnan;
        float inv_a = 1.0f / ((a > EPSF) ? a : 1.0f);
        float inv_c = 1.0f / ((cc > EPSF) ? cc : 1.0f);
        float ee2 = __fsub_rn(__fadd_rn(a, cc), __fmul_rn(2.0f, b));
        float inv_ee2 = 1.0f / ((ee2 > EPSF) ? ee2 : 1.0f);
        float det2 = __fsub_rn(__fmul_rn(e0[0], e1[1]), __fmul_rn(e1[0], e0[1]));
        float inv_det2s = (fabsf(det2) > EPSF) ? (1.0f / det2) : qnan;
        float* o = s_fd + i * 20;
        o[0] = v0[0]; o[1] = v0[1]; o[2] = v0[2];
        o[3] = e0[0]; o[4] = e0[1]; o[5] = e0[2];
        o[6] = e1[0]; o[7] = e1[1]; o[8] = e1[2];
        o[9] = a; o[10] = b; o[11] = cc;
        o[12] = inv_det; o[13] = inv_a; o[14] = inv_c;
        o[15] = ee2; o[16] = inv_ee2; o[17] = inv_det2s;
        o[18] = __fsub_rn(b, a); o[19] = 0.f;
    }
    for (int i = t; i < 2048; i += NTHR) s_d2[i] = 0x7f800000u;
    if (t < 64) s_pm[t] = 0u;
    __syncthreads();

    // ---------- phase C: z-folded hot loop (bit-identical math to R4/R5) ----------
    {
        int col = cg * 64 + lane;           // gy*32+gx
        int gx = col & 31, gy = col >> 5;
        float px = __fadd_rn(-1.0f, __fmul_rn((float)gx, step));
        float py = __fadd_rn(-1.0f, __fmul_rn((float)gy, step));

        int wvu = __builtin_amdgcn_readfirstlane(wvid);

        float dmin[32];
#pragma unroll
        for (int k = 0; k < 32; ++k) dmin[k] = 3.402823466e38f;
        unsigned cmask = 0u;

        // round-robin faces across the 16 waves: balanced SIMD loads; min/xor
        // combines are exactly commutative so any partition is bit-exact.
        for (int i = wvu; i < nloc; i += 16) {
            const float4* q4 = (const float4*)(s_fd + i * 20);  // 80B-aligned
            float4 r0 = q4[0], r1 = q4[1], r2 = q4[2], r3 = q4[3], r4 = q4[4];
            float v0x = r0.x, v0y = r0.y, v0z = r0.z;
            float e0x = r0.w, e0y = r1.x, e0z = r1.y;
            float e1x = r1.z, e1y = r1.w, e1z = r2.x;
            float a = r2.y, b = r2.z, cc = r2.w;
            float inv_det = r3.x, inv_a = r3.y, inv_c = r3.z;
            float ee2 = r3.w, inv_ee2 = r4.x, inv_det2s = r4.y;
            float bma = r4.z;

            float wx = __fsub_rn(px, v0x), wy = __fsub_rn(py, v0y);
            float ffxy = wx * wx + wy * wy;
            float de0xy = wx * e0x + wy * e0y;
            float de1xy = wx * e1x + wy * e1y;

            float u2n = __fsub_rn(__fmul_rn(wx, e1y), __fmul_rn(wy, e1x));
            float v2n = __fsub_rn(__fmul_rn(e0x, wy), __fmul_rn(e0y, wx));
            float u2 = __fmul_rn(u2n, inv_det2s);
            float v2 = __fmul_rn(v2n, inv_det2s);
            bool in2d = (u2 >= 0.0f) & (v2 >= 0.0f) & (__fadd_rn(u2, v2) <= 1.0f);
            float zint = __fadd_rn(__fadd_rn(v0z, __fmul_rn(u2, e0z)), __fmul_rn(v2, e1z));
            int c = 0;
            {
                float p;
                p = __fadd_rn(-1.0f, __fmul_rn((float)(15), step));      if (zint > p) c = 16;
                p = __fadd_rn(-1.0f, __fmul_rn((float)(c + 7), step));   if (zint > p) c += 8;
                p = __fadd_rn(-1.0f, __fmul_rn((float)(c + 3), step));   if (zint > p) c += 4;
                p = __fadd_rn(-1.0f, __fmul_rn((float)(c + 1), step));   if (zint > p) c += 2;
                p = __fadd_rn(-1.0f, __fmul_rn((float)(c), step));       if (zint > p) c += 1;
                p = __fadd_rn(-1.0f, __fmul_rn((float)(c), step));       if (zint > p) c += 1;
            }
            unsigned mask = (c == 0) ? 0u : (0xffffffffu >> (32 - c));
            cmask ^= in2d ? mask : 0u;

#pragma unroll
            for (int k = 0; k < 32; ++k) {
                const float pzk = -1.0f + (float)k * (2.0f / 31.0f);
                float wz = __fsub_rn(pzk, v0z);
                float ff = fmaf(wz, wz, ffxy);
                float de0 = fmaf(wz, e0z, de0xy);
                float de1 = fmaf(wz, e1z, de1xy);
                float u = (cc * de0 - b * de1) * inv_det;
                float v = (a * de1 - b * de0) * inv_det;
                bool inside = (u >= 0.0f) & (v >= 0.0f) & (u + v <= 1.0f);
                float plane_d2 = ff - (u * de0 + v * de1);
                float t0 = fminf(fmaxf(de0 * inv_a, 0.0f), 1.0f);
                float d2_0 = ff + t0 * (t0 * a - 2.0f * de0);
                float t1 = fminf(fmaxf(de1 * inv_c, 0.0f), 1.0f);
                float d2_1 = ff + t1 * (t1 * cc - 2.0f * de1);
                float dot2 = (de1 - de0) - bma;
                float w1sq = ff - 2.0f * de0 + a;
                float t2 = fminf(fmaxf(dot2 * inv_ee2, 0.0f), 1.0f);
                float d2_2 = w1sq + t2 * (t2 * ee2 - 2.0f * dot2);
                float ed2 = fminf(fminf(d2_0, d2_1), d2_2);
                float d2 = inside ? plane_d2 : ed2;
                dmin[k] = fminf(dmin[k], fmaxf(d2, 0.0f));
            }
        }

        // block combine (LDS), then device-scope atomics into ws buffers
#pragma unroll
        for (int k = 0; k < 32; ++k)
            atomicMin(&s_d2[k * 64 + lane], __float_as_uint(dmin[k]));
        atomicXor(&s_pm[lane], cmask);
        __syncthreads();
        for (int i = t; i < 2048; i += NTHR) {
            int k = i >> 6, ln = i & 63;
            atomicMin(&d2u[k * NCOL + cg * 64 + ln], s_d2[i]);
        }
        if (t < 64) atomicXor(&parm[cg * 64 + t], s_pm[t]);
    }

    // ---------- completion counter: last block finishes ----------
    __threadfence();
    __syncthreads();
    if (t == 0) {
        unsigned old = atomicAdd(counter, 1u);   // base 0xFFFFFFFF from memset
        s_last = (old == (unsigned)(NBLK - 2)) ? 1u : 0u;
    }
    __syncthreads();
    if (s_last == 0u) return;
    __threadfence();

    // ---------- finisher (one block): o-bbox + overlap + sample + loss ----------
    {
        float onx = INFINITY, ony = INFINITY, onz = INFINITY;
        float oxx = -INFINITY, oxy = -INFINITY, oxz = -INFINITY;
        for (int j = t; j < no; j += NTHR) {
            float x = ov[3 * j], y = ov[3 * j + 1], z = ov[3 * j + 2];
            onx = fminf(onx, x); ony = fminf(ony, y); onz = fminf(onz, z);
            oxx = fmaxf(oxx, x); oxy = fmaxf(oxy, y); oxz = fmaxf(oxz, z);
        }
        onx = wmin64(onx); ony = wmin64(ony); onz = wmin64(onz);
        oxx = wmax64(oxx); oxy = wmax64(oxy); oxz = wmax64(oxz);
        if (lane == 0) {
            s_w[wvid][0] = onx; s_w[wvid][1] = ony; s_w[wvid][2] = onz;
            s_w[wvid][3] = oxx; s_w[wvid][4] = oxy; s_w[wvid][5] = oxz;
        }
        __syncthreads();
        if (wvid == 0) {
            float a0 = (lane < 16) ? s_w[lane][0] : INFINITY;
            float a1 = (lane < 16) ? s_w[lane][1] : INFINITY;
            float a2 = (lane < 16) ? s_w[lane][2] : INFINITY;
            float a3 = (lane < 16) ? s_w[lane][3] : -INFINITY;
            float a4 = (lane < 16) ? s_w[lane][4] : -INFINITY;
            float a5 = (lane < 16) ? s_w[lane][5] : -INFINITY;
            a0 = wmin64(a0); a1 = wmin64(a1); a2 = wmin64(a2);
            a3 = wmax64(a3); a4 = wmax64(a4); a5 = wmax64(a5);
            if (lane == 0) {
                bool ovl = (s_hb[0] <= a3) && (s_hb[1] <= a4) && (s_hb[2] <= a5) &&
                           (a0 <= s_hb[3]) && (a1 <= s_hb[4]) && (a2 <= s_hb[5]);
                s_ovl = ovl ? 1.0f : 0.0f;
            }
        }
        __syncthreads();
        float acc = 0.0f;
        for (int j = t; j < no; j += NTHR) {
            float qx = __fdiv_rn(__fsub_rn(ov[3 * j + 0], cx), sc);
            float qy = __fdiv_rn(__fsub_rn(ov[3 * j + 1], cy), sc);
            float qz = __fdiv_rn(__fsub_rn(ov[3 * j + 2], cz), sc);
            float fx = __fmul_rn(__fmul_rn(__fadd_rn(qx, 1.0f), 0.5f), 31.0f);
            float fy = __fmul_rn(__fmul_rn(__fadd_rn(qy, 1.0f), 0.5f), 31.0f);
            float fz = __fmul_rn(__fmul_rn(__fadd_rn(qz, 1.0f), 0.5f), 31.0f);
            float flx = floorf(fx), fly = floorf(fy), flz = floorf(fz);
            int ix0 = (int)flx, iy0 = (int)fly, iz0 = (int)flz;
            float w1x = __fsub_rn(fx, flx), w0x = __fsub_rn(1.0f, w1x);
            float w1y = __fsub_rn(fy, fly), w0y = __fsub_rn(1.0f, w1y);
            float w1z = __fsub_rn(fz, flz), w0z = __fsub_rn(1.0f, w1z);
            for (int dz = 0; dz < 2; ++dz)
                for (int dy = 0; dy < 2; ++dy)
                    for (int dx = 0; dx < 2; ++dx) {
                        int ix = ix0 + dx, iy = iy0 + dy, iz = iz0 + dz;
                        bool valid = (ix >= 0) & (ix < GN) & (iy >= 0) & (iy < GN) &
                                     (iz >= 0) & (iz < GN);
                        if (valid) {
                            // agent-scope loads: coherent vs other XCDs' atomics
                            unsigned pmv = __hip_atomic_load(&parm[iy * GN + ix],
                                                __ATOMIC_RELAXED, __HIP_MEMORY_SCOPE_AGENT);
                            unsigned pm = pmv ^ 0xFFFFFFFFu;   // remove memset base
                            float val = 0.0f;
                            if ((pm >> iz) & 1u) {
                                unsigned du = __hip_atomic_load(&d2u[(iz * GN + iy) * GN + ix],
                                                __ATOMIC_RELAXED, __HIP_MEMORY_SCOPE_AGENT);
                                val = sqrtf(__uint_as_float(du));
                            }
                            float wgt = __fmul_rn(__fmul_rn(dx ? w1x : w0x, dy ? w1y : w0y),
                                                  dz ? w1z : w0z);
                            acc = __fadd_rn(acc, __fmul_rn(val, wgt));
                        }
                    }
        }
        acc = wsum64(acc);
        if (lane == 0) s_w[wvid][6] = acc;
        __syncthreads();
        if (wvid == 0) {
            float v = (lane < 16) ? s_w[lane][6] : 0.0f;
            v = wsum64(v);
            if (lane == 0) {
                float loss = __fmul_rn(v, v);
                out[0] = (s_ovl != 0.0f) ? loss : 0.0f;
            }
        }
    }
}

extern "C" void kernel_launch(void* const* d_in, const int* in_sizes, int n_in,
                              void* d_out, int out_size, void* d_ws, size_t ws_size,
                              hipStream_t stream) {
    const float* hv = (const float*)d_in[0];
    const float* ov = (const float*)d_in[1];
    const int* faces = (const int*)d_in[2];
    int nh = in_sizes[0] / 3;
    int no = in_sizes[1] / 3;
    int nf = in_sizes[2] / 3;

    unsigned* d2u = (unsigned*)d_ws;          // NPTS u32
    unsigned* parm = d2u + NPTS;              // NCOL u32
    unsigned* counter = parm + NCOL;          // 1 u32 (+pad)

    // one node: init d2u=UINT_MAX (atomicMin top), parm=0xFFFFFFFF (XOR base,
    // removed in finisher), counter=0xFFFFFFFF (add base; 256th old == 254)
    hipMemsetAsync(d_ws, 0xFF, (size_t)(NPTS + NCOL + 16) * 4, stream);
    k_all<<<NBLK, NTHR, 0, stream>>>(hv, nh, ov, no, faces, nf,
                                     d2u, parm, counter, (float*)d_out);
}